// Round 12
// baseline (220.623 us; speedup 1.0000x reference)
//
#include <hip/hip_runtime.h>

#define KNN 30
#define FDIM 64
#define HDIM 64

typedef short s8v __attribute__((ext_vector_type(8)));   // 8 bf16 bit-patterns (4 VGPR)
typedef unsigned short u16x8 __attribute__((ext_vector_type(8)));
typedef float f4v __attribute__((ext_vector_type(4)));   // MFMA accumulator
typedef unsigned long long u64;

// round-to-nearest-even f32 -> bf16 bits
static __device__ __forceinline__ unsigned short f2bf(float f) {
  unsigned int u = __builtin_bit_cast(unsigned int, f);
  u += 0x7fffu + ((u >> 16) & 1u);
  return (unsigned short)(u >> 16);
}
static __device__ __forceinline__ float bf2f(unsigned short h) {
  unsigned int u = ((unsigned int)h) << 16;
  return __builtin_bit_cast(float, u);
}

// f32 bits -> order-preserving u32 (asc float order == asc uint order)
static __device__ __forceinline__ unsigned int f2sort(float f) {
  unsigned int u = __builtin_bit_cast(unsigned int, f);
  unsigned int m = (unsigned int)(((int)u) >> 31) | 0x80000000u;
  return u ^ m;
}

// XOR swizzle (ushort-index space): byte ^= (row&7)<<4  <=>  idx ^= (row&7)<<3
static __device__ __forceinline__ int swzi(int row, int col, int roww) {
  return (row * roww + col) ^ ((row & 7) << 3);
}

static __device__ __forceinline__ void lds_fence() {
  asm volatile("s_waitcnt lgkmcnt(0)" ::: "memory");
  __builtin_amdgcn_sched_barrier(0);
}

static __device__ __forceinline__ s8v pack8(float4 a, float4 b) {
  s8v v;
  v[0] = (short)f2bf(a.x); v[1] = (short)f2bf(a.y);
  v[2] = (short)f2bf(a.z); v[3] = (short)f2bf(a.w);
  v[4] = (short)f2bf(b.x); v[5] = (short)f2bf(b.y);
  v[6] = (short)f2bf(b.z); v[7] = (short)f2bf(b.w);
  return v;
}

// ---------------- prep: xbf = bf16(x) and sq = |x|^2 (exact f32) ----------------
__global__ __launch_bounds__(256) void prep_kernel(const float* __restrict__ x,
                                                   unsigned short* __restrict__ xbf,
                                                   float* __restrict__ sq) {
  int t = threadIdx.x;
  int r = blockIdx.x * 32 + (t >> 3);
  int sub = t & 7;
  const float* p = x + (size_t)r * FDIM + sub * 8;
  float4 a = *reinterpret_cast<const float4*>(p);
  float4 b = *reinterpret_cast<const float4*>(p + 4);
  *reinterpret_cast<s8v*>(xbf + (size_t)r * FDIM + sub * 8) = pack8(a, b);
  float s = a.x * a.x;
  s = fmaf(a.y, a.y, s); s = fmaf(a.z, a.z, s); s = fmaf(a.w, a.w, s);
  s = fmaf(b.x, b.x, s); s = fmaf(b.y, b.y, s); s = fmaf(b.z, b.z, s);
  s = fmaf(b.w, b.w, s);
  s += __shfl_xor(s, 1);
  s += __shfl_xor(s, 2);
  s += __shfl_xor(s, 4);
  if (sub == 0) sq[r] = s;
}

// ---------------- U/P precompute (layer-1 algebraic elimination) ----------------
__global__ __launch_bounds__(256) void uP_kernel(const float* __restrict__ x,
                                                 const float* __restrict__ W1,
                                                 const float* __restrict__ b1,
                                                 float* __restrict__ U,
                                                 unsigned short* __restrict__ P) {
  __shared__ __align__(16) unsigned short sWT[128 * 64];
  int t = threadIdx.x;
  for (int e = t; e < 64 * 64; e += 256) {
    int f = e >> 6, h = e & 63;
    float wa = W1[f * 64 + h];
    float wb = W1[(64 + f) * 64 + h];
    sWT[swzi(h, f, 64)] = f2bf(wa + wb);
    sWT[swzi(64 + h, f, 64)] = f2bf(wb);
  }
  __syncthreads();
  int wv = t >> 6, lane = t & 63;
  int q = lane >> 4, cl = lane & 15;
  int base = blockIdx.x * 128 + wv * 32;

  s8v af[2][2];
#pragma unroll
  for (int mt = 0; mt < 2; ++mt)
#pragma unroll
    for (int ks = 0; ks < 2; ++ks) {
      const float* px = x + (size_t)(base + mt * 16 + cl) * FDIM + ks * 32 + q * 8;
      float4 a = *reinterpret_cast<const float4*>(px);
      float4 b = *reinterpret_cast<const float4*>(px + 4);
      af[mt][ks] = pack8(a, b);
    }
  f4v acc[2][8];
#pragma unroll
  for (int nt = 0; nt < 8; ++nt) {
    float bb = (nt < 4) ? b1[nt * 16 + cl] : 0.0f;
    f4v a0 = {bb, bb, bb, bb};
    acc[0][nt] = a0;
    acc[1][nt] = a0;
  }
#pragma unroll
  for (int ks = 0; ks < 2; ++ks)
#pragma unroll
    for (int nt = 0; nt < 8; ++nt) {
      s8v wf = *reinterpret_cast<const s8v*>(&sWT[swzi(nt * 16 + cl, ks * 32 + q * 8, 64)]);
      acc[0][nt] = __builtin_amdgcn_mfma_f32_16x16x32_bf16(af[0][ks], wf, acc[0][nt], 0, 0, 0);
      acc[1][nt] = __builtin_amdgcn_mfma_f32_16x16x32_bf16(af[1][ks], wf, acc[1][nt], 0, 0, 0);
    }
#pragma unroll
  for (int mt = 0; mt < 2; ++mt)
#pragma unroll
    for (int nt = 0; nt < 8; ++nt)
#pragma unroll
      for (int i = 0; i < 4; ++i) {
        int row = base + mt * 16 + q * 4 + i;
        if (nt < 4) U[(size_t)row * 64 + nt * 16 + cl] = acc[mt][nt][i];
        else        P[(size_t)row * 64 + (nt - 4) * 16 + cl] = f2bf(acc[mt][nt][i]);
      }
}

// ---------------- dist16 v3: register-direct bf16 MFMA Gram -> u16 keys (R6-validated) ----
__global__ __launch_bounds__(256) void dist16_kernel(const unsigned short* __restrict__ xbf,
                                                     const float* __restrict__ sq,
                                                     unsigned short* __restrict__ D16,
                                                     int R0, int V) {
  __shared__ __align__(16) unsigned short sK[128 * 128];  // 32KB key tile
  int t = threadIdx.x;
  int R = R0 + blockIdx.y * 128;
  int b = R / V;
  int w0 = blockIdx.x * 128;
  size_t bbase = (size_t)b * V;
  int wv = t >> 6, lane = t & 63;
  int q = lane >> 4, cl = lane & 15;
  int mq = wv >> 1, nq = wv & 1;  // 64x64 quadrant per wave

  s8v af[4][2], bfr[4][2];
#pragma unroll
  for (int mt = 0; mt < 4; ++mt)
#pragma unroll
    for (int ks = 0; ks < 2; ++ks) {
      af[mt][ks] = *reinterpret_cast<const s8v*>(
          xbf + (size_t)(R + mq * 64 + mt * 16 + cl) * FDIM + ks * 32 + q * 8);
      bfr[mt][ks] = *reinterpret_cast<const s8v*>(
          xbf + (bbase + (size_t)(w0 + nq * 64 + mt * 16 + cl)) * FDIM + ks * 32 + q * 8);
    }
  f4v acc[4][4];
#pragma unroll
  for (int mt = 0; mt < 4; ++mt)
#pragma unroll
    for (int nt = 0; nt < 4; ++nt) {
      f4v z = {0.0f, 0.0f, 0.0f, 0.0f};
      acc[mt][nt] = z;
    }
#pragma unroll
  for (int ks = 0; ks < 2; ++ks)
#pragma unroll
    for (int mt = 0; mt < 4; ++mt)
#pragma unroll
      for (int nt = 0; nt < 4; ++nt)
        acc[mt][nt] = __builtin_amdgcn_mfma_f32_16x16x32_bf16(af[mt][ks], bfr[nt][ks], acc[mt][nt], 0, 0, 0);
  float sql[4];
#pragma unroll
  for (int nt = 0; nt < 4; ++nt) sql[nt] = sq[bbase + w0 + nq * 64 + nt * 16 + cl];

  // keys -> LDS (row-swizzled)
#pragma unroll
  for (int mt = 0; mt < 4; ++mt)
#pragma unroll
    for (int nt = 0; nt < 4; ++nt)
#pragma unroll
      for (int i = 0; i < 4; ++i) {
        int rl = mq * 64 + mt * 16 + q * 4 + i;
        int cll = nq * 64 + nt * 16 + cl;
        float dk = fmaf(-128.0f, acc[mt][nt][i], fmaf(64.0f, sql[nt], 16384.0f));
        int ki = (int)(dk + 0.5f);
        ki = ki < 0 ? 0 : (ki > 65535 ? 65535 : ki);
        sK[rl * 128 + (cll ^ ((rl & 7) << 3))] = (unsigned short)ki;
      }
  __syncthreads();

  // coalesced store: 8-lane group writes one row's 256B contiguously
  {
    int sub = t & 7, rbase = t >> 3;
#pragma unroll
    for (int i = 0; i < 4; ++i) {
      int rr = i * 32 + rbase;
      int sw = (rr & 7) << 3;
      int c1 = (sub * 16) ^ sw;
      int c2 = (sub * 16 + 8) ^ sw;
      s8v k0 = *reinterpret_cast<const s8v*>(&sK[rr * 128 + c1]);
      s8v k1 = *reinterpret_cast<const s8v*>(&sK[rr * 128 + c2]);
      size_t gb = (size_t)(blockIdx.y * 128 + rr) * (size_t)V + w0 + sub * 16;
      *reinterpret_cast<s8v*>(D16 + gb) = k0;
      *reinterpret_cast<s8v*>(D16 + gb + 8) = k1;
    }
  }
}

// exhaustive exact per-row fallback (pathological clustering only; field-validated R9)
static __device__ void knn_exhaustive(int R, const float* __restrict__ x,
                                      const float* __restrict__ sq, size_t bbase,
                                      int* __restrict__ idxout, int lane, u64* scratch) {
  float* sXv = reinterpret_cast<float*>(scratch);
  sXv[lane] = x[(size_t)R * FDIM + lane];
  lds_fence();
  unsigned int sve[32];
#pragma unroll 1
  for (int rr = 0; rr < 32; ++rr) {
    int w = rr * 64 + lane;
    const float* xw = x + (bbase + (unsigned)w) * FDIM;
    float dot = 0.f;
    for (int f = 0; f < FDIM; ++f) dot = fmaf(sXv[f], xw[f], dot);
    sve[rr] = f2sort(fmaf(-2.f, dot, sq[bbase + (unsigned)w]));
  }
  unsigned removed = 0;
  for (int it = 0; it < KNN + 1; ++it) {
    u64 m2 = ~0ULL;
#pragma unroll
    for (int rr = 0; rr < 32; ++rr) {
      u64 key = ((u64)sve[rr] << 32) | (unsigned)(rr * 64 + lane);
      bool alive = ((removed >> rr) & 1u) == 0u;
      if (alive && key < m2) m2 = key;
    }
    u64 gk = m2;
#pragma unroll
    for (int off = 32; off; off >>= 1) {
      u64 o = __shfl_xor(gk, off);
      gk = (o < gk) ? o : gk;
    }
    if (it > 0 && lane == 0)
      idxout[(size_t)R * KNN + (it - 1)] = (int)(unsigned)(gk & 0xFFFFFFFFu);
#pragma unroll
    for (int rr = 0; rr < 32; ++rr) {
      u64 key = ((u64)sve[rr] << 32) | (unsigned)(rr * 64 + lane);
      if (key == gk) removed |= (1u << rr);
    }
  }
  lds_fence();
}

// ---------------- topk16 v4: TWO rows per wave (ILP overlap of latency chains) ----------
// Selection semantics per row identical to R6-validated: tau = rank-30 of 64 per-lane
// key minima + 66 margin; compact; exact fp32 rescan; rank-count select (R8-validated).
__global__ __launch_bounds__(256) void topk16_kernel(const unsigned short* __restrict__ D16,
                                                     const float* __restrict__ x,
                                                     const float* __restrict__ sq,
                                                     int* __restrict__ idxout,
                                                     int R0, int nrows, int V) {
  __shared__ unsigned int pool[8][128];
  __shared__ __align__(16) u64 pool2[8][136];
  int wave = threadIdx.x >> 6, lane = threadIdx.x & 63;
  int rA = blockIdx.x * 8 + wave * 2;  // local rows (nrows multiple of 128 -> always valid pair)
  int rB = rA + 1;
  int RA = R0 + rA, RB = R0 + rB;
  int b = RA / V;  // rA even => pair never straddles a batch boundary
  size_t bbase = (size_t)b * V;
  int sA2 = wave * 2, sB2 = wave * 2 + 1;
  const unsigned short* rowA = D16 + (size_t)rA * V;
  const unsigned short* rowB = D16 + (size_t)rB * V;

  // 32 keys/lane/row; value (s,j) at col s*512 + lane*8 + j
  u16x8 ka0 = *reinterpret_cast<const u16x8*>(rowA + 0 * 512 + lane * 8);
  u16x8 ka1 = *reinterpret_cast<const u16x8*>(rowA + 1 * 512 + lane * 8);
  u16x8 ka2 = *reinterpret_cast<const u16x8*>(rowA + 2 * 512 + lane * 8);
  u16x8 ka3 = *reinterpret_cast<const u16x8*>(rowA + 3 * 512 + lane * 8);
  u16x8 kb0 = *reinterpret_cast<const u16x8*>(rowB + 0 * 512 + lane * 8);
  u16x8 kb1 = *reinterpret_cast<const u16x8*>(rowB + 1 * 512 + lane * 8);
  u16x8 kb2 = *reinterpret_cast<const u16x8*>(rowB + 2 * 512 + lane * 8);
  u16x8 kb3 = *reinterpret_cast<const u16x8*>(rowB + 3 * 512 + lane * 8);

  // per-lane mins (packed)
  u16x8 mA = __builtin_elementwise_min(__builtin_elementwise_min(ka0, ka1),
                                       __builtin_elementwise_min(ka2, ka3));
  u16x8 mB = __builtin_elementwise_min(__builtin_elementwise_min(kb0, kb1),
                                       __builtin_elementwise_min(kb2, kb3));
  unsigned int mnA = mA[0], mnB = mB[0];
#pragma unroll
  for (int j = 1; j < 8; ++j) {
    mnA = min(mnA, (unsigned int)mA[j]);
    mnB = min(mnB, (unsigned int)mB[j]);
  }

  // dual bitonic-64 of lane minima (two independent chains interleaved)
  unsigned int sA = mnA, sB = mnB;
#pragma unroll
  for (int k = 2; k <= 64; k <<= 1) {
#pragma unroll
    for (int j = k >> 1; j > 0; j >>= 1) {
      unsigned int oA = __shfl_xor(sA, j);
      unsigned int oB = __shfl_xor(sB, j);
      bool keep_min = ((lane & k) == 0) == ((lane & j) == 0);
      sA = (keep_min == (sA < oA)) ? sA : oA;
      sB = (keep_min == (sB < oB)) ? sB : oB;
    }
  }
  unsigned int tauA = __shfl(sA, 30) + 66;
  unsigned int tauB = __shfl(sB, 30) + 66;

  // counts + dual prefix sum
  int cntA = 0, cntB = 0;
#pragma unroll
  for (int j = 0; j < 8; ++j) {
    cntA += (ka0[j] <= tauA) + (ka1[j] <= tauA) + (ka2[j] <= tauA) + (ka3[j] <= tauA);
    cntB += (kb0[j] <= tauB) + (kb1[j] <= tauB) + (kb2[j] <= tauB) + (kb3[j] <= tauB);
  }
  int preA = cntA, preB = cntB;
#pragma unroll
  for (int off = 1; off < 64; off <<= 1) {
    int oA = __shfl_up(preA, off);
    int oB = __shfl_up(preB, off);
    if (lane >= off) { preA += oA; preB += oB; }
  }
  int totA = __shfl(preA, 63), totB = __shfl(preB, 63);
  int baseA = preA - cntA, baseB = preB - cntB;
  bool okA = totA <= 128, okB = totB <= 128;

  // scatter candidates (combined key<<16|w)
  if (okA) {
    int slot = baseA;
#pragma unroll
    for (int j = 0; j < 8; ++j) {
      if (ka0[j] <= tauA) { pool[sA2][slot] = ((unsigned)ka0[j] << 16) | (unsigned)(0 * 512 + lane * 8 + j); slot++; }
      if (ka1[j] <= tauA) { pool[sA2][slot] = ((unsigned)ka1[j] << 16) | (unsigned)(1 * 512 + lane * 8 + j); slot++; }
      if (ka2[j] <= tauA) { pool[sA2][slot] = ((unsigned)ka2[j] << 16) | (unsigned)(2 * 512 + lane * 8 + j); slot++; }
      if (ka3[j] <= tauA) { pool[sA2][slot] = ((unsigned)ka3[j] << 16) | (unsigned)(3 * 512 + lane * 8 + j); slot++; }
    }
  }
  if (okB) {
    int slot = baseB;
#pragma unroll
    for (int j = 0; j < 8; ++j) {
      if (kb0[j] <= tauB) { pool[sB2][slot] = ((unsigned)kb0[j] << 16) | (unsigned)(0 * 512 + lane * 8 + j); slot++; }
      if (kb1[j] <= tauB) { pool[sB2][slot] = ((unsigned)kb1[j] << 16) | (unsigned)(1 * 512 + lane * 8 + j); slot++; }
      if (kb2[j] <= tauB) { pool[sB2][slot] = ((unsigned)kb2[j] << 16) | (unsigned)(2 * 512 + lane * 8 + j); slot++; }
      if (kb3[j] <= tauB) { pool[sB2][slot] = ((unsigned)kb3[j] << 16) | (unsigned)(3 * 512 + lane * 8 + j); slot++; }
    }
  }
  lds_fence();

  // exact fp32 rescan, interleaved across the two rows
  int g8 = lane >> 3, sub = lane & 7;
  const float* xap = x + (size_t)RA * FDIM + sub * 8;
  const float* xbp = x + (size_t)RB * FDIM + sub * 8;
  float4 xa0 = *reinterpret_cast<const float4*>(xap);
  float4 xa1 = *reinterpret_cast<const float4*>(xap + 4);
  float4 xb0 = *reinterpret_cast<const float4*>(xbp);
  float4 xb1 = *reinterpret_cast<const float4*>(xbp + 4);
  int rndA = okA ? (totA + 7) >> 3 : 0;
  int rndB = okB ? (totB + 7) >> 3 : 0;
  int rnds = rndA > rndB ? rndA : rndB;
  for (int it = 0; it < rnds; ++it) {
    int c = it * 8 + g8;
    if (it < rndA) {
      unsigned pk = pool[sA2][c < totA ? c : 0];
      int w = (int)(pk & 0xFFFFu);
      const float* xwp = x + (bbase + (unsigned)w) * FDIM + sub * 8;
      float4 w0 = *reinterpret_cast<const float4*>(xwp);
      float4 w1 = *reinterpret_cast<const float4*>(xwp + 4);
      float dot = xa0.x * w0.x;
      dot = fmaf(xa0.y, w0.y, dot); dot = fmaf(xa0.z, w0.z, dot);
      dot = fmaf(xa0.w, w0.w, dot); dot = fmaf(xa1.x, w1.x, dot);
      dot = fmaf(xa1.y, w1.y, dot); dot = fmaf(xa1.z, w1.z, dot);
      dot = fmaf(xa1.w, w1.w, dot);
      dot += __shfl_xor(dot, 1);
      dot += __shfl_xor(dot, 2);
      dot += __shfl_xor(dot, 4);
      float dx = fmaf(-2.f, dot, sq[bbase + (unsigned)w]);
      if (sub == 0 && c < totA) pool2[sA2][c] = ((u64)f2sort(dx) << 32) | (unsigned)w;
    }
    if (it < rndB) {
      unsigned pk = pool[sB2][c < totB ? c : 0];
      int w = (int)(pk & 0xFFFFu);
      const float* xwp = x + (bbase + (unsigned)w) * FDIM + sub * 8;
      float4 w0 = *reinterpret_cast<const float4*>(xwp);
      float4 w1 = *reinterpret_cast<const float4*>(xwp + 4);
      float dot = xb0.x * w0.x;
      dot = fmaf(xb0.y, w0.y, dot); dot = fmaf(xb0.z, w0.z, dot);
      dot = fmaf(xb0.w, w0.w, dot); dot = fmaf(xb1.x, w1.x, dot);
      dot = fmaf(xb1.y, w1.y, dot); dot = fmaf(xb1.z, w1.z, dot);
      dot = fmaf(xb1.w, w1.w, dot);
      dot += __shfl_xor(dot, 1);
      dot += __shfl_xor(dot, 2);
      dot += __shfl_xor(dot, 4);
      float dx = fmaf(-2.f, dot, sq[bbase + (unsigned)w]);
      if (sub == 0 && c < totB) pool2[sB2][c] = ((u64)f2sort(dx) << 32) | (unsigned)w;
    }
  }
  int nbA = okA ? ((totA + 7) & ~7) : 0;
  int nbB = okB ? ((totB + 7) & ~7) : 0;
  if (okA && lane < nbA - totA) pool2[sA2][totA + lane] = ~0ULL;
  if (okB && lane < nbB - totB) pool2[sB2][totB + lane] = ~0ULL;
  lds_fence();

  // rank-count select (keys unique -> rank = exact stable position; rank 0 = self)
  if (okA) {
    u64 k1 = pool2[sA2][lane];
    u64 k2 = (64 + lane < nbA) ? pool2[sA2][64 + lane] : ~0ULL;
    int r1 = 0, r2 = 0;
    for (int d0 = 0; d0 < nbA; d0 += 8) {
#pragma unroll
      for (int u = 0; u < 8; ++u) {
        u64 v = pool2[sA2][d0 + u];
        r1 += (v < k1);
        r2 += (v < k2);
      }
    }
    if (lane < totA && r1 >= 1 && r1 <= KNN)
      idxout[(size_t)RA * KNN + (r1 - 1)] = (int)(unsigned)(k1 & 0xFFFFFFFFu);
    if (64 + lane < totA && r2 >= 1 && r2 <= KNN)
      idxout[(size_t)RA * KNN + (r2 - 1)] = (int)(unsigned)(k2 & 0xFFFFFFFFu);
  }
  if (okB) {
    u64 k1 = pool2[sB2][lane];
    u64 k2 = (64 + lane < nbB) ? pool2[sB2][64 + lane] : ~0ULL;
    int r1 = 0, r2 = 0;
    for (int d0 = 0; d0 < nbB; d0 += 8) {
#pragma unroll
      for (int u = 0; u < 8; ++u) {
        u64 v = pool2[sB2][d0 + u];
        r1 += (v < k1);
        r2 += (v < k2);
      }
    }
    if (lane < totB && r1 >= 1 && r1 <= KNN)
      idxout[(size_t)RB * KNN + (r1 - 1)] = (int)(unsigned)(k1 & 0xFFFFFFFFu);
    if (64 + lane < totB && r2 >= 1 && r2 <= KNN)
      idxout[(size_t)RB * KNN + (r2 - 1)] = (int)(unsigned)(k2 & 0xFFFFFFFFu);
  }

  if (!okA) knn_exhaustive(RA, x, sq, bbase, idxout, lane, &pool2[sA2][0]);
  if (!okB) knn_exhaustive(RB, x, sq, bbase, idxout, lane, &pool2[sB2][0]);
}

// ---------------- mlp v3: register-direct H1 A-frags (no H1 LDS round trip) ----------
// Lane (q,cl) gathers exactly its MFMA A-fragment: rows nb(cl) and nb(min(16+cl,29)),
// k-chunks ks*32+q*8. H1 = relu(U[v]-P[nb]) built straight into af2 registers.
// Only remaining LDS round trip: H2 transpose (1 fence). idx shfl broadcast eliminated.
__global__ __launch_bounds__(256) void mlp_kernel(const float* __restrict__ U,
                                                  const unsigned short* __restrict__ P,
                                                  const int* __restrict__ idx,
                                                  const float* __restrict__ W2,
                                                  const float* __restrict__ b2,
                                                  const float* __restrict__ W3,
                                                  const float* __restrict__ b3,
                                                  float* __restrict__ out, int V) {
  __shared__ __align__(16) unsigned short sW2T[HDIM * HDIM];
  __shared__ __align__(16) unsigned short sW3T[HDIM * HDIM];
  __shared__ __align__(16) unsigned short sScr[4][2048];
  int t = threadIdx.x;
  for (int e = t; e < HDIM * HDIM; e += 256) {
    int i = e >> 6, j = e & 63;
    sW2T[swzi(j, i, 64)] = f2bf(W2[e]);
    int s = (i & 15) * 4 + (i >> 4);
    sW3T[swzi(j, s, 64)] = f2bf(W3[e]);
  }
  __syncthreads();

  int wv = t >> 6, lane = t & 63;
  int q = lane >> 4, cl = lane & 15;
  unsigned short* scr = &sScr[wv][0];
  float bias2[4], bias3[4];
#pragma unroll
  for (int nt = 0; nt < 4; ++nt) {
    bias2[nt] = b2[nt * 16 + cl];
    bias3[nt] = b3[nt * 16 + cl];
  }

  int kkA = cl;                                   // rows 0..15 (<30, no clamp)
  int kkB = (16 + cl < KNN) ? 16 + cl : KNN - 1;  // rows 16..31 (30,31 -> 29)
  int vbase = blockIdx.x * 16 + wv * 4;
  int b = vbase / V;  // 4 consecutive vertices never straddle a batch
  size_t bbase = (size_t)b * V;

  for (int vi = 0; vi < 4; ++vi) {
    int v = vbase + vi;
    int nbA = idx[(size_t)v * KNN + kkA];
    int nbB = idx[(size_t)v * KNN + kkB];
    const float* up = U + (size_t)v * 64;
    float4 u00 = *reinterpret_cast<const float4*>(up + q * 8);
    float4 u01 = *reinterpret_cast<const float4*>(up + q * 8 + 4);
    float4 u10 = *reinterpret_cast<const float4*>(up + 32 + q * 8);
    float4 u11 = *reinterpret_cast<const float4*>(up + 32 + q * 8 + 4);
    const unsigned short* pA = P + (bbase + (unsigned)nbA) * 64;
    const unsigned short* pB = P + (bbase + (unsigned)nbB) * 64;
    s8v pA0 = *reinterpret_cast<const s8v*>(pA + q * 8);
    s8v pA1 = *reinterpret_cast<const s8v*>(pA + 32 + q * 8);
    s8v pB0 = *reinterpret_cast<const s8v*>(pB + q * 8);
    s8v pB1 = *reinterpret_cast<const s8v*>(pB + 32 + q * 8);

    float uk0[8] = {u00.x, u00.y, u00.z, u00.w, u01.x, u01.y, u01.z, u01.w};
    float uk1[8] = {u10.x, u10.y, u10.z, u10.w, u11.x, u11.y, u11.z, u11.w};
    s8v afA0, afA1, afB0, afB1;  // af2[mt=A/B][ks=0/1]
#pragma unroll
    for (int j = 0; j < 8; ++j) {
      afA0[j] = (short)f2bf(fmaxf(uk0[j] - bf2f((unsigned short)pA0[j]), 0.0f));
      afA1[j] = (short)f2bf(fmaxf(uk1[j] - bf2f((unsigned short)pA1[j]), 0.0f));
      afB0[j] = (short)f2bf(fmaxf(uk0[j] - bf2f((unsigned short)pB0[j]), 0.0f));
      afB1[j] = (short)f2bf(fmaxf(uk1[j] - bf2f((unsigned short)pB1[j]), 0.0f));
    }

    // ---- layer 2 (A-frags in registers) ----
    f4v acc2[2][4];
#pragma unroll
    for (int mt = 0; mt < 2; ++mt)
#pragma unroll
      for (int nt = 0; nt < 4; ++nt) {
        f4v a0 = {bias2[nt], bias2[nt], bias2[nt], bias2[nt]};
        acc2[mt][nt] = a0;
      }
#pragma unroll
    for (int nt = 0; nt < 4; ++nt) {
      s8v wf0 = *reinterpret_cast<const s8v*>(&sW2T[swzi(nt * 16 + cl, 0 * 32 + q * 8, 64)]);
      s8v wf1 = *reinterpret_cast<const s8v*>(&sW2T[swzi(nt * 16 + cl, 1 * 32 + q * 8, 64)]);
      acc2[0][nt] = __builtin_amdgcn_mfma_f32_16x16x32_bf16(afA0, wf0, acc2[0][nt], 0, 0, 0);
      acc2[1][nt] = __builtin_amdgcn_mfma_f32_16x16x32_bf16(afB0, wf0, acc2[1][nt], 0, 0, 0);
      acc2[0][nt] = __builtin_amdgcn_mfma_f32_16x16x32_bf16(afA1, wf1, acc2[0][nt], 0, 0, 0);
      acc2[1][nt] = __builtin_amdgcn_mfma_f32_16x16x32_bf16(afB1, wf1, acc2[1][nt], 0, 0, 0);
    }

    // relu -> H2, nt-interleaved packed b64 stores
#pragma unroll
    for (int mt = 0; mt < 2; ++mt)
#pragma unroll
      for (int i = 0; i < 4; ++i) {
        int m = mt * 16 + q * 4 + i;
        u64 pk = 0;
#pragma unroll
        for (int nt = 0; nt < 4; ++nt) {
          u64 hb = f2bf(fmaxf(acc2[mt][nt][i], 0.0f));
          pk |= hb << (16 * nt);
        }
        *reinterpret_cast<u64*>(&scr[swzi(m, cl * 4, 64)]) = pk;
      }
    lds_fence();

    // ---- layer 3 (s-permuted k-dim) ----
    s8v af3[2][2];
#pragma unroll
    for (int mt = 0; mt < 2; ++mt)
#pragma unroll
      for (int ks = 0; ks < 2; ++ks)
        af3[mt][ks] = *reinterpret_cast<const s8v*>(&scr[swzi(mt * 16 + cl, ks * 32 + q * 8, 64)]);
    f4v acc3[2][4];
#pragma unroll
    for (int mt = 0; mt < 2; ++mt)
#pragma unroll
      for (int nt = 0; nt < 4; ++nt) {
        f4v a0 = {bias3[nt], bias3[nt], bias3[nt], bias3[nt]};
        acc3[mt][nt] = a0;
      }
#pragma unroll
    for (int ks = 0; ks < 2; ++ks)
#pragma unroll
      for (int nt = 0; nt < 4; ++nt) {
        s8v wf = *reinterpret_cast<const s8v*>(&sW3T[swzi(nt * 16 + cl, ks * 32 + q * 8, 64)]);
        acc3[0][nt] = __builtin_amdgcn_mfma_f32_16x16x32_bf16(af3[0][ks], wf, acc3[0][nt], 0, 0, 0);
        acc3[1][nt] = __builtin_amdgcn_mfma_f32_16x16x32_bf16(af3[1][ks], wf, acc3[1][nt], 0, 0, 0);
      }

    float m[4] = {0.0f, 0.0f, 0.0f, 0.0f};
#pragma unroll
    for (int nt = 0; nt < 4; ++nt)
#pragma unroll
      for (int mt = 0; mt < 2; ++mt)
#pragma unroll
        for (int i = 0; i < 4; ++i) m[nt] = fmaxf(m[nt], acc3[mt][nt][i]);
#pragma unroll
    for (int nt = 0; nt < 4; ++nt) {
      m[nt] = fmaxf(m[nt], __shfl_xor(m[nt], 16));
      m[nt] = fmaxf(m[nt], __shfl_xor(m[nt], 32));
    }
    float outv = (q == 0) ? m[0] : (q == 1) ? m[1] : (q == 2) ? m[2] : m[3];
    out[(size_t)v * HDIM + lane] = outv;

    lds_fence();  // scr (H2) reuse guard for next vertex
  }
}

extern "C" void kernel_launch(void* const* d_in, const int* in_sizes, int n_in,
                              void* d_out, int out_size, void* d_ws, size_t ws_size,
                              hipStream_t stream) {
  const float* x  = (const float*)d_in[0];
  const float* W1 = (const float*)d_in[2];
  const float* b1 = (const float*)d_in[3];
  const float* W2 = (const float*)d_in[4];
  const float* b2 = (const float*)d_in[5];
  const float* W3 = (const float*)d_in[6];
  const float* b3 = (const float*)d_in[7];
  float* out = (float*)d_out;
  int N = in_sizes[0] / FDIM;      // 32768
  int B = in_sizes[1] - 1;         // 16
  int V = N / B;                   // 2048

  char* ws = (char*)d_ws;
  float* sqbuf = (float*)ws;
  size_t off = (size_t)N * sizeof(float);
  int* idxbuf = (int*)(ws + off);
  off += (size_t)N * KNN * sizeof(int);
  off = (off + 255) & ~(size_t)255;
  float* Ubuf = (float*)(ws + off);
  off += (size_t)N * 64 * sizeof(float);
  unsigned short* Pbuf = (unsigned short*)(ws + off);
  off += (size_t)N * 64 * sizeof(unsigned short);
  off = (off + 255) & ~(size_t)255;
  unsigned short* xbfbuf = (unsigned short*)(ws + off);
  off += (size_t)N * 64 * sizeof(unsigned short);
  off = (off + 255) & ~(size_t)255;
  unsigned short* D16buf = (unsigned short*)(ws + off);
  size_t dcap = (ws_size > off) ? (ws_size - off) : 0;
  long long capRows = (long long)(dcap / ((size_t)V * sizeof(unsigned short)));
  capRows &= ~127LL;
  if (capRows > N) capRows = N;
  if (capRows < 128) capRows = 128;  // requires sufficient ws_size

  prep_kernel<<<N / 32, 256, 0, stream>>>(x, xbfbuf, sqbuf);
  uP_kernel<<<N / 128, 256, 0, stream>>>(x, W1, b1, Ubuf, Pbuf);
  for (int R0 = 0; R0 < N; R0 += (int)capRows) {
    int nr = N - R0;
    if (nr > capRows) nr = (int)capRows;
    dim3 g(V / 128, nr / 128);
    dist16_kernel<<<g, 256, 0, stream>>>(xbfbuf, sqbuf, D16buf, R0, V);
    topk16_kernel<<<nr / 8, 256, 0, stream>>>(D16buf, x, sqbuf, idxbuf, R0, nr, V);
  }
  mlp_kernel<<<N / 16, 256, 0, stream>>>(Ubuf, Pbuf, idxbuf, W2, b2, W3, b3, out, V);
}

// Round 13
// 196.403 us; speedup vs baseline: 1.1233x; 1.1233x over previous
//
#include <hip/hip_runtime.h>

#define KNN 30
#define FDIM 64
#define HDIM 64

typedef short s8v __attribute__((ext_vector_type(8)));   // 8 bf16 bit-patterns (4 VGPR)
typedef unsigned short u16x8 __attribute__((ext_vector_type(8)));
typedef float f4v __attribute__((ext_vector_type(4)));   // MFMA accumulator
typedef unsigned long long u64;

// round-to-nearest-even f32 -> bf16 bits
static __device__ __forceinline__ unsigned short f2bf(float f) {
  unsigned int u = __builtin_bit_cast(unsigned int, f);
  u += 0x7fffu + ((u >> 16) & 1u);
  return (unsigned short)(u >> 16);
}
static __device__ __forceinline__ float bf2f(unsigned short h) {
  unsigned int u = ((unsigned int)h) << 16;
  return __builtin_bit_cast(float, u);
}

// f32 bits -> order-preserving u32 (asc float order == asc uint order)
static __device__ __forceinline__ unsigned int f2sort(float f) {
  unsigned int u = __builtin_bit_cast(unsigned int, f);
  unsigned int m = (unsigned int)(((int)u) >> 31) | 0x80000000u;
  return u ^ m;
}

// XOR swizzle (ushort-index space): byte ^= (row&7)<<4  <=>  idx ^= (row&7)<<3
static __device__ __forceinline__ int swzi(int row, int col, int roww) {
  return (row * roww + col) ^ ((row & 7) << 3);
}

// full fence: drains LDS + blocks scheduler (kept where hand-ordering is required)
static __device__ __forceinline__ void lds_fence() {
  asm volatile("s_waitcnt lgkmcnt(0)" ::: "memory");
  __builtin_amdgcn_sched_barrier(0);
}
// compiler-only barrier: orders the C++ LDS accesses (type-pun alias guard) but lets
// the HW scheduler overlap. Same-wave ds ops execute in issue order; the compiler
// inserts its own lgkmcnt for the register dependency of the dependent ds_read.
static __device__ __forceinline__ void compiler_fence() {
  asm volatile("" ::: "memory");
}

static __device__ __forceinline__ s8v pack8(float4 a, float4 b) {
  s8v v;
  v[0] = (short)f2bf(a.x); v[1] = (short)f2bf(a.y);
  v[2] = (short)f2bf(a.z); v[3] = (short)f2bf(a.w);
  v[4] = (short)f2bf(b.x); v[5] = (short)f2bf(b.y);
  v[6] = (short)f2bf(b.z); v[7] = (short)f2bf(b.w);
  return v;
}

// ---------------- uP (merged prep): U/P precompute + xbf + exact sq ----------------
// U[v] = x_v @ (W1a+W1b) + b1 (f32); P[v] = x_v @ W1b (bf16);
// xbf = bf16(x) (the already-packed A fragments); sq = |x_v|^2 exact f32.
__global__ __launch_bounds__(256) void uP_kernel(const float* __restrict__ x,
                                                 const float* __restrict__ W1,
                                                 const float* __restrict__ b1,
                                                 float* __restrict__ U,
                                                 unsigned short* __restrict__ P,
                                                 unsigned short* __restrict__ xbf,
                                                 float* __restrict__ sq) {
  __shared__ __align__(16) unsigned short sWT[128 * 64];
  int t = threadIdx.x;
  for (int e = t; e < 64 * 64; e += 256) {
    int f = e >> 6, h = e & 63;
    float wa = W1[f * 64 + h];
    float wb = W1[(64 + f) * 64 + h];
    sWT[swzi(h, f, 64)] = f2bf(wa + wb);
    sWT[swzi(64 + h, f, 64)] = f2bf(wb);
  }
  __syncthreads();
  int wv = t >> 6, lane = t & 63;
  int q = lane >> 4, cl = lane & 15;
  int base = blockIdx.x * 128 + wv * 32;

  s8v af[2][2];
  float ss0 = 0.0f, ss1 = 0.0f;
#pragma unroll
  for (int mt = 0; mt < 2; ++mt)
#pragma unroll
    for (int ks = 0; ks < 2; ++ks) {
      int row = base + mt * 16 + cl;
      const float* px = x + (size_t)row * FDIM + ks * 32 + q * 8;
      float4 a = *reinterpret_cast<const float4*>(px);
      float4 b = *reinterpret_cast<const float4*>(px + 4);
      af[mt][ks] = pack8(a, b);
      *reinterpret_cast<s8v*>(xbf + (size_t)row * FDIM + ks * 32 + q * 8) = af[mt][ks];
      float s = a.x * a.x;
      s = fmaf(a.y, a.y, s); s = fmaf(a.z, a.z, s); s = fmaf(a.w, a.w, s);
      s = fmaf(b.x, b.x, s); s = fmaf(b.y, b.y, s); s = fmaf(b.z, b.z, s);
      s = fmaf(b.w, b.w, s);
      if (mt == 0) ss0 += s; else ss1 += s;
    }
  // per-row |x|^2: reduce over the 4 q-lanes holding the same row
  ss0 += __shfl_xor(ss0, 16); ss0 += __shfl_xor(ss0, 32);
  ss1 += __shfl_xor(ss1, 16); ss1 += __shfl_xor(ss1, 32);
  if (q == 0) {
    sq[base + cl] = ss0;
    sq[base + 16 + cl] = ss1;
  }

  f4v acc[2][8];
#pragma unroll
  for (int nt = 0; nt < 8; ++nt) {
    float bb = (nt < 4) ? b1[nt * 16 + cl] : 0.0f;
    f4v a0 = {bb, bb, bb, bb};
    acc[0][nt] = a0;
    acc[1][nt] = a0;
  }
#pragma unroll
  for (int ks = 0; ks < 2; ++ks)
#pragma unroll
    for (int nt = 0; nt < 8; ++nt) {
      s8v wf = *reinterpret_cast<const s8v*>(&sWT[swzi(nt * 16 + cl, ks * 32 + q * 8, 64)]);
      acc[0][nt] = __builtin_amdgcn_mfma_f32_16x16x32_bf16(af[0][ks], wf, acc[0][nt], 0, 0, 0);
      acc[1][nt] = __builtin_amdgcn_mfma_f32_16x16x32_bf16(af[1][ks], wf, acc[1][nt], 0, 0, 0);
    }
#pragma unroll
  for (int mt = 0; mt < 2; ++mt)
#pragma unroll
    for (int nt = 0; nt < 8; ++nt)
#pragma unroll
      for (int i = 0; i < 4; ++i) {
        int row = base + mt * 16 + q * 4 + i;
        if (nt < 4) U[(size_t)row * 64 + nt * 16 + cl] = acc[mt][nt][i];
        else        P[(size_t)row * 64 + (nt - 4) * 16 + cl] = f2bf(acc[mt][nt][i]);
      }
}

// ---------------- dist16 v3: register-direct bf16 MFMA Gram -> u16 keys (R6-validated) ----
__global__ __launch_bounds__(256) void dist16_kernel(const unsigned short* __restrict__ xbf,
                                                     const float* __restrict__ sq,
                                                     unsigned short* __restrict__ D16,
                                                     int R0, int V) {
  __shared__ __align__(16) unsigned short sK[128 * 128];  // 32KB key tile
  int t = threadIdx.x;
  int R = R0 + blockIdx.y * 128;
  int b = R / V;
  int w0 = blockIdx.x * 128;
  size_t bbase = (size_t)b * V;
  int wv = t >> 6, lane = t & 63;
  int q = lane >> 4, cl = lane & 15;
  int mq = wv >> 1, nq = wv & 1;  // 64x64 quadrant per wave

  s8v af[4][2], bfr[4][2];
#pragma unroll
  for (int mt = 0; mt < 4; ++mt)
#pragma unroll
    for (int ks = 0; ks < 2; ++ks) {
      af[mt][ks] = *reinterpret_cast<const s8v*>(
          xbf + (size_t)(R + mq * 64 + mt * 16 + cl) * FDIM + ks * 32 + q * 8);
      bfr[mt][ks] = *reinterpret_cast<const s8v*>(
          xbf + (bbase + (size_t)(w0 + nq * 64 + mt * 16 + cl)) * FDIM + ks * 32 + q * 8);
    }
  f4v acc[4][4];
#pragma unroll
  for (int mt = 0; mt < 4; ++mt)
#pragma unroll
    for (int nt = 0; nt < 4; ++nt) {
      f4v z = {0.0f, 0.0f, 0.0f, 0.0f};
      acc[mt][nt] = z;
    }
#pragma unroll
  for (int ks = 0; ks < 2; ++ks)
#pragma unroll
    for (int mt = 0; mt < 4; ++mt)
#pragma unroll
      for (int nt = 0; nt < 4; ++nt)
        acc[mt][nt] = __builtin_amdgcn_mfma_f32_16x16x32_bf16(af[mt][ks], bfr[nt][ks], acc[mt][nt], 0, 0, 0);
  float sql[4];
#pragma unroll
  for (int nt = 0; nt < 4; ++nt) sql[nt] = sq[bbase + w0 + nq * 64 + nt * 16 + cl];

  // keys -> LDS (row-swizzled)
#pragma unroll
  for (int mt = 0; mt < 4; ++mt)
#pragma unroll
    for (int nt = 0; nt < 4; ++nt)
#pragma unroll
      for (int i = 0; i < 4; ++i) {
        int rl = mq * 64 + mt * 16 + q * 4 + i;
        int cll = nq * 64 + nt * 16 + cl;
        float dk = fmaf(-128.0f, acc[mt][nt][i], fmaf(64.0f, sql[nt], 16384.0f));
        int ki = (int)(dk + 0.5f);
        ki = ki < 0 ? 0 : (ki > 65535 ? 65535 : ki);
        sK[rl * 128 + (cll ^ ((rl & 7) << 3))] = (unsigned short)ki;
      }
  __syncthreads();

  // coalesced store: 8-lane group writes one row's 256B contiguously
  {
    int sub = t & 7, rbase = t >> 3;
#pragma unroll
    for (int i = 0; i < 4; ++i) {
      int rr = i * 32 + rbase;
      int sw = (rr & 7) << 3;
      int c1 = (sub * 16) ^ sw;
      int c2 = (sub * 16 + 8) ^ sw;
      s8v k0 = *reinterpret_cast<const s8v*>(&sK[rr * 128 + c1]);
      s8v k1 = *reinterpret_cast<const s8v*>(&sK[rr * 128 + c2]);
      size_t gb = (size_t)(blockIdx.y * 128 + rr) * (size_t)V + w0 + sub * 16;
      *reinterpret_cast<s8v*>(D16 + gb) = k0;
      *reinterpret_cast<s8v*>(D16 + gb + 8) = k1;
    }
  }
}

// ---------------- topk16 v2 (R6-validated, 84.5us — declared structural floor) --------
// Margin: |d_bf16 - d_fp32| <= E (=0.5, ~10 sigma) -> 128E+2 = 66 key units.
// tau = rank-30 of the 64 per-lane key minima (upper bound on true rank-31 key).
__global__ __launch_bounds__(256) void topk16_kernel(const unsigned short* __restrict__ D16,
                                                     const float* __restrict__ x,
                                                     const float* __restrict__ sq,
                                                     int* __restrict__ idxout,
                                                     int R0, int nrows, int V) {
  __shared__ unsigned int pool[4][128];
  __shared__ u64 pool2[4][128];
  __shared__ float sXv[4][64];
  int wave = threadIdx.x >> 6, lane = threadIdx.x & 63;
  int rowL = blockIdx.x * 4 + wave;
  if (rowL >= nrows) return;
  int R = R0 + rowL;
  int b = R / V;
  size_t bbase = (size_t)b * V;
  const unsigned short* row16 = D16 + (size_t)rowL * (size_t)V;

  u16x8 r0 = *reinterpret_cast<const u16x8*>(row16 + 0 * 512 + lane * 8);
  u16x8 r1 = *reinterpret_cast<const u16x8*>(row16 + 1 * 512 + lane * 8);
  u16x8 r2 = *reinterpret_cast<const u16x8*>(row16 + 2 * 512 + lane * 8);
  u16x8 r3 = *reinterpret_cast<const u16x8*>(row16 + 3 * 512 + lane * 8);

  u16x8 m01 = __builtin_elementwise_min(r0, r1);
  u16x8 m23 = __builtin_elementwise_min(r2, r3);
  u16x8 m = __builtin_elementwise_min(m01, m23);
  unsigned int mn = m[0];
#pragma unroll
  for (int j = 1; j < 8; ++j) mn = min(mn, (unsigned int)m[j]);

  unsigned int srt = mn;
#pragma unroll
  for (int k = 2; k <= 64; k <<= 1) {
#pragma unroll
    for (int j = k >> 1; j > 0; j >>= 1) {
      unsigned int o = __shfl_xor(srt, j);
      bool keep_min = ((lane & k) == 0) == ((lane & j) == 0);
      bool less = srt < o;
      srt = (keep_min == less) ? srt : o;
    }
  }
  unsigned int tauk = __shfl(srt, 30) + 66;

  int cnt = 0;
#pragma unroll
  for (int j = 0; j < 8; ++j) {
    cnt += (r0[j] <= tauk);
    cnt += (r1[j] <= tauk);
    cnt += (r2[j] <= tauk);
    cnt += (r3[j] <= tauk);
  }
  int pre = cnt;
#pragma unroll
  for (int off = 1; off < 64; off <<= 1) {
    int o = __shfl_up(pre, off);
    if (lane >= off) pre += o;
  }
  int total = __shfl(pre, 63);
  int mybase = pre - cnt;

  if (total <= 128) {
    int slot = mybase;
#pragma unroll
    for (int j = 0; j < 8; ++j) {
      if (r0[j] <= tauk) { pool[wave][slot] = ((unsigned int)r0[j] << 16) | (unsigned int)(0 * 512 + lane * 8 + j); slot++; }
      if (r1[j] <= tauk) { pool[wave][slot] = ((unsigned int)r1[j] << 16) | (unsigned int)(1 * 512 + lane * 8 + j); slot++; }
      if (r2[j] <= tauk) { pool[wave][slot] = ((unsigned int)r2[j] << 16) | (unsigned int)(2 * 512 + lane * 8 + j); slot++; }
      if (r3[j] <= tauk) { pool[wave][slot] = ((unsigned int)r3[j] << 16) | (unsigned int)(3 * 512 + lane * 8 + j); slot++; }
    }
    lds_fence();
    int base = total;
    int g = lane >> 3, sub = lane & 7;
    const float* xvp = x + (size_t)R * FDIM + sub * 8;
    float4 xv0 = *reinterpret_cast<const float4*>(xvp);
    float4 xv1 = *reinterpret_cast<const float4*>(xvp + 4);
    float xv[8] = {xv0.x, xv0.y, xv0.z, xv0.w, xv1.x, xv1.y, xv1.z, xv1.w};
    int rounds = (base + 7) >> 3;
    for (int it = 0; it < rounds; ++it) {
      int c = it * 8 + g;
      unsigned int pk = pool[wave][c < base ? c : 0];
      int w = (int)(pk & 0xFFFFu);
      const float* xwp = x + (bbase + (unsigned int)w) * FDIM + sub * 8;
      float4 b0 = *reinterpret_cast<const float4*>(xwp);
      float4 b1 = *reinterpret_cast<const float4*>(xwp + 4);
      float dot = xv[0] * b0.x;
      dot = fmaf(xv[1], b0.y, dot); dot = fmaf(xv[2], b0.z, dot);
      dot = fmaf(xv[3], b0.w, dot); dot = fmaf(xv[4], b1.x, dot);
      dot = fmaf(xv[5], b1.y, dot); dot = fmaf(xv[6], b1.z, dot);
      dot = fmaf(xv[7], b1.w, dot);
      dot += __shfl_xor(dot, 1);
      dot += __shfl_xor(dot, 2);
      dot += __shfl_xor(dot, 4);
      float dx = fmaf(-2.0f, dot, sq[bbase + (unsigned int)w]);
      if (sub == 0 && c < base)
        pool2[wave][c] = ((u64)f2sort(dx) << 32) | (unsigned int)w;
    }
    lds_fence();
    u64 keyA = (lane < base) ? pool2[wave][lane] : ~0ULL;
    if (base <= 64) {
#pragma unroll
      for (int k = 2; k <= 64; k <<= 1) {
#pragma unroll
        for (int j = k >> 1; j > 0; j >>= 1) {
          u64 o = __shfl_xor(keyA, j);
          bool keep_min = ((lane & k) == 0) == ((lane & j) == 0);
          bool less = keyA < o;
          keyA = (keep_min == less) ? keyA : o;
        }
      }
      if (lane >= 1 && lane <= KNN)
        idxout[(size_t)R * KNN + (lane - 1)] = (int)(unsigned int)(keyA & 0xFFFFFFFFu);
    } else {
      u64 keyB = (64 + lane < base) ? pool2[wave][64 + lane] : ~0ULL;
#pragma unroll
      for (int k = 2; k <= 64; k <<= 1) {
#pragma unroll
        for (int j = k >> 1; j > 0; j >>= 1) {
          u64 oA = __shfl_xor(keyA, j);
          bool keep_min = ((lane & k) == 0) == ((lane & j) == 0);
          keyA = (keep_min == (keyA < oA)) ? keyA : oA;
          u64 oB = __shfl_xor(keyB, j);
          keyB = (keep_min == (keyB < oB)) ? keyB : oB;
        }
      }
      u64 keyBr = __shfl(keyB, 63 - lane);
      u64 mnk = keyA < keyBr ? keyA : keyBr;
#pragma unroll
      for (int j = 32; j > 0; j >>= 1) {
        u64 o = __shfl_xor(mnk, j);
        bool keep_min = (lane & j) == 0;
        mnk = (keep_min == (mnk < o)) ? mnk : o;
      }
      if (lane >= 1 && lane <= KNN)
        idxout[(size_t)R * KNN + (lane - 1)] = (int)(unsigned int)(mnk & 0xFFFFFFFFu);
    }
  } else {
    // exhaustive exact fallback (pathological clustering only): full row in fp32
    sXv[wave][lane] = x[(size_t)R * FDIM + lane];
    lds_fence();
    unsigned int sve[32];
#pragma unroll 1
    for (int s = 0; s < 4; ++s)
#pragma unroll 1
      for (int j = 0; j < 8; ++j) {
        int w = s * 512 + lane * 8 + j;
        const float* xw = x + (bbase + (unsigned int)w) * FDIM;
        float dot = 0.0f;
        for (int f = 0; f < 64; ++f) dot = fmaf(sXv[wave][f], xw[f], dot);
        sve[s * 8 + j] = f2sort(fmaf(-2.0f, dot, sq[bbase + (unsigned int)w]));
      }
    unsigned int removed = 0;
    for (int it = 0; it < KNN + 1; ++it) {
      u64 m2 = ~0ULL;
#pragma unroll
      for (int r = 0; r < 32; ++r) {
        u64 key = ((u64)sve[r] << 32) | (unsigned int)((r >> 3) * 512 + lane * 8 + (r & 7));
        bool alive = ((removed >> r) & 1u) == 0u;
        if (alive && key < m2) m2 = key;
      }
      u64 gk = m2;
#pragma unroll
      for (int off = 32; off; off >>= 1) {
        u64 o = __shfl_xor(gk, off);
        gk = (o < gk) ? o : gk;
      }
      if (it > 0 && lane == 0) idxout[(size_t)R * KNN + (it - 1)] = (int)(unsigned int)(gk & 0xFFFFFFFFu);
#pragma unroll
      for (int r = 0; r < 32; ++r) {
        u64 key = ((u64)sve[r] << 32) | (unsigned int)((r >> 3) * 512 + lane * 8 + (r & 7));
        if (key == gk) removed |= (1u << r);
      }
    }
  }
}

// ---------------- mlp v4: register-direct H1 + compiler-only fences ----------------
// v3 structure (field-validated R12) with the sched_barrier/waitcnt fences replaced by
// compiler barriers: same-wave LDS ops execute in issue order, and the compiler inserts
// its own lgkmcnt for the ds_read->MFMA register dependency. This lets vertex v+1's
// idx/U/P gathers overlap vertex v's MFMA/pack phases.
__global__ __launch_bounds__(256) void mlp_kernel(const float* __restrict__ U,
                                                  const unsigned short* __restrict__ P,
                                                  const int* __restrict__ idx,
                                                  const float* __restrict__ W2,
                                                  const float* __restrict__ b2,
                                                  const float* __restrict__ W3,
                                                  const float* __restrict__ b3,
                                                  float* __restrict__ out, int V) {
  __shared__ __align__(16) unsigned short sW2T[HDIM * HDIM];
  __shared__ __align__(16) unsigned short sW3T[HDIM * HDIM];
  __shared__ __align__(16) unsigned short sScr[4][2048];
  int t = threadIdx.x;
  for (int e = t; e < HDIM * HDIM; e += 256) {
    int i = e >> 6, j = e & 63;
    sW2T[swzi(j, i, 64)] = f2bf(W2[e]);
    int s = (i & 15) * 4 + (i >> 4);
    sW3T[swzi(j, s, 64)] = f2bf(W3[e]);
  }
  __syncthreads();

  int wv = t >> 6, lane = t & 63;
  int q = lane >> 4, cl = lane & 15;
  unsigned short* scr = &sScr[wv][0];
  float bias2[4], bias3[4];
#pragma unroll
  for (int nt = 0; nt < 4; ++nt) {
    bias2[nt] = b2[nt * 16 + cl];
    bias3[nt] = b3[nt * 16 + cl];
  }

  int kkA = cl;                                   // rows 0..15 (<30, no clamp)
  int kkB = (16 + cl < KNN) ? 16 + cl : KNN - 1;  // rows 16..31 (30,31 -> 29)
  int vbase = blockIdx.x * 16 + wv * 4;
  int b = vbase / V;  // 4 consecutive vertices never straddle a batch
  size_t bbase = (size_t)b * V;

  for (int vi = 0; vi < 4; ++vi) {
    int v = vbase + vi;
    int nbA = idx[(size_t)v * KNN + kkA];
    int nbB = idx[(size_t)v * KNN + kkB];
    const float* up = U + (size_t)v * 64;
    float4 u00 = *reinterpret_cast<const float4*>(up + q * 8);
    float4 u01 = *reinterpret_cast<const float4*>(up + q * 8 + 4);
    float4 u10 = *reinterpret_cast<const float4*>(up + 32 + q * 8);
    float4 u11 = *reinterpret_cast<const float4*>(up + 32 + q * 8 + 4);
    const unsigned short* pA = P + (bbase + (unsigned)nbA) * 64;
    const unsigned short* pB = P + (bbase + (unsigned)nbB) * 64;
    s8v pA0 = *reinterpret_cast<const s8v*>(pA + q * 8);
    s8v pA1 = *reinterpret_cast<const s8v*>(pA + 32 + q * 8);
    s8v pB0 = *reinterpret_cast<const s8v*>(pB + q * 8);
    s8v pB1 = *reinterpret_cast<const s8v*>(pB + 32 + q * 8);

    float uk0[8] = {u00.x, u00.y, u00.z, u00.w, u01.x, u01.y, u01.z, u01.w};
    float uk1[8] = {u10.x, u10.y, u10.z, u10.w, u11.x, u11.y, u11.z, u11.w};
    s8v afA0, afA1, afB0, afB1;  // af2[mt=A/B][ks=0/1]
#pragma unroll
    for (int j = 0; j < 8; ++j) {
      afA0[j] = (short)f2bf(fmaxf(uk0[j] - bf2f((unsigned short)pA0[j]), 0.0f));
      afA1[j] = (short)f2bf(fmaxf(uk1[j] - bf2f((unsigned short)pA1[j]), 0.0f));
      afB0[j] = (short)f2bf(fmaxf(uk0[j] - bf2f((unsigned short)pB0[j]), 0.0f));
      afB1[j] = (short)f2bf(fmaxf(uk1[j] - bf2f((unsigned short)pB1[j]), 0.0f));
    }

    // ---- layer 2 (A-frags in registers) ----
    f4v acc2[2][4];
#pragma unroll
    for (int mt = 0; mt < 2; ++mt)
#pragma unroll
      for (int nt = 0; nt < 4; ++nt) {
        f4v a0 = {bias2[nt], bias2[nt], bias2[nt], bias2[nt]};
        acc2[mt][nt] = a0;
      }
#pragma unroll
    for (int nt = 0; nt < 4; ++nt) {
      s8v wf0 = *reinterpret_cast<const s8v*>(&sW2T[swzi(nt * 16 + cl, 0 * 32 + q * 8, 64)]);
      s8v wf1 = *reinterpret_cast<const s8v*>(&sW2T[swzi(nt * 16 + cl, 1 * 32 + q * 8, 64)]);
      acc2[0][nt] = __builtin_amdgcn_mfma_f32_16x16x32_bf16(afA0, wf0, acc2[0][nt], 0, 0, 0);
      acc2[1][nt] = __builtin_amdgcn_mfma_f32_16x16x32_bf16(afB0, wf0, acc2[1][nt], 0, 0, 0);
      acc2[0][nt] = __builtin_amdgcn_mfma_f32_16x16x32_bf16(afA1, wf1, acc2[0][nt], 0, 0, 0);
      acc2[1][nt] = __builtin_amdgcn_mfma_f32_16x16x32_bf16(afB1, wf1, acc2[1][nt], 0, 0, 0);
    }

    // relu -> H2, nt-interleaved packed b64 stores
#pragma unroll
    for (int mt = 0; mt < 2; ++mt)
#pragma unroll
      for (int i = 0; i < 4; ++i) {
        int m = mt * 16 + q * 4 + i;
        u64 pk = 0;
#pragma unroll
        for (int nt = 0; nt < 4; ++nt) {
          u64 hb = f2bf(fmaxf(acc2[mt][nt][i], 0.0f));
          pk |= hb << (16 * nt);
        }
        *reinterpret_cast<u64*>(&scr[swzi(m, cl * 4, 64)]) = pk;
      }
    compiler_fence();  // order H2 stores before af3 reads (type-pun alias guard)

    // ---- layer 3 (s-permuted k-dim) ----
    s8v af3[2][2];
#pragma unroll
    for (int mt = 0; mt < 2; ++mt)
#pragma unroll
      for (int ks = 0; ks < 2; ++ks)
        af3[mt][ks] = *reinterpret_cast<const s8v*>(&scr[swzi(mt * 16 + cl, ks * 32 + q * 8, 64)]);
    f4v acc3[2][4];
#pragma unroll
    for (int mt = 0; mt < 2; ++mt)
#pragma unroll
      for (int nt = 0; nt < 4; ++nt) {
        f4v a0 = {bias3[nt], bias3[nt], bias3[nt], bias3[nt]};
        acc3[mt][nt] = a0;
      }
#pragma unroll
    for (int ks = 0; ks < 2; ++ks)
#pragma unroll
      for (int nt = 0; nt < 4; ++nt) {
        s8v wf = *reinterpret_cast<const s8v*>(&sW3T[swzi(nt * 16 + cl, ks * 32 + q * 8, 64)]);
        acc3[0][nt] = __builtin_amdgcn_mfma_f32_16x16x32_bf16(af3[0][ks], wf, acc3[0][nt], 0, 0, 0);
        acc3[1][nt] = __builtin_amdgcn_mfma_f32_16x16x32_bf16(af3[1][ks], wf, acc3[1][nt], 0, 0, 0);
      }

    float m[4] = {0.0f, 0.0f, 0.0f, 0.0f};
#pragma unroll
    for (int nt = 0; nt < 4; ++nt)
#pragma unroll
      for (int mt = 0; mt < 2; ++mt)
#pragma unroll
        for (int i = 0; i < 4; ++i) m[nt] = fmaxf(m[nt], acc3[mt][nt][i]);
#pragma unroll
    for (int nt = 0; nt < 4; ++nt) {
      m[nt] = fmaxf(m[nt], __shfl_xor(m[nt], 16));
      m[nt] = fmaxf(m[nt], __shfl_xor(m[nt], 32));
    }
    float outv = (q == 0) ? m[0] : (q == 1) ? m[1] : (q == 2) ? m[2] : m[3];
    out[(size_t)v * HDIM + lane] = outv;

    compiler_fence();  // order af3 reads before next vertex's H2 stores (same-wave scr reuse)
  }
}

extern "C" void kernel_launch(void* const* d_in, const int* in_sizes, int n_in,
                              void* d_out, int out_size, void* d_ws, size_t ws_size,
                              hipStream_t stream) {
  const float* x  = (const float*)d_in[0];
  const float* W1 = (const float*)d_in[2];
  const float* b1 = (const float*)d_in[3];
  const float* W2 = (const float*)d_in[4];
  const float* b2 = (const float*)d_in[5];
  const float* W3 = (const float*)d_in[6];
  const float* b3 = (const float*)d_in[7];
  float* out = (float*)d_out;
  int N = in_sizes[0] / FDIM;      // 32768
  int B = in_sizes[1] - 1;         // 16
  int V = N / B;                   // 2048

  char* ws = (char*)d_ws;
  float* sqbuf = (float*)ws;
  size_t off = (size_t)N * sizeof(float);
  int* idxbuf = (int*)(ws + off);
  off += (size_t)N * KNN * sizeof(int);
  off = (off + 255) & ~(size_t)255;
  float* Ubuf = (float*)(ws + off);
  off += (size_t)N * 64 * sizeof(float);
  unsigned short* Pbuf = (unsigned short*)(ws + off);
  off += (size_t)N * 64 * sizeof(unsigned short);
  off = (off + 255) & ~(size_t)255;
  unsigned short* xbfbuf = (unsigned short*)(ws + off);
  off += (size_t)N * 64 * sizeof(unsigned short);
  off = (off + 255) & ~(size_t)255;
  unsigned short* D16buf = (unsigned short*)(ws + off);
  size_t dcap = (ws_size > off) ? (ws_size - off) : 0;
  long long capRows = (long long)(dcap / ((size_t)V * sizeof(unsigned short)));
  capRows &= ~127LL;
  if (capRows > N) capRows = N;
  if (capRows < 128) capRows = 128;  // requires sufficient ws_size

  uP_kernel<<<N / 128, 256, 0, stream>>>(x, W1, b1, Ubuf, Pbuf, xbfbuf, sqbuf);
  for (int R0 = 0; R0 < N; R0 += (int)capRows) {
    int nr = N - R0;
    if (nr > capRows) nr = (int)capRows;
    dim3 g(V / 128, nr / 128);
    dist16_kernel<<<g, 256, 0, stream>>>(xbfbuf, sqbuf, D16buf, R0, V);
    topk16_kernel<<<nr / 4, 256, 0, stream>>>(D16buf, x, sqbuf, idxbuf, R0, nr, V);
  }
  mlp_kernel<<<N / 16, 256, 0, stream>>>(Ubuf, Pbuf, idxbuf, W2, b2, W3, b3, out, V);
}